// Round 1
// baseline (518.775 us; speedup 1.0000x reference)
//
#include <hip/hip_runtime.h>

// ChebConv K=3, D=64. Strategy: build in-degree CSR (counts -> scan -> fill),
// then two atomic-free gather propagations, one wave (64 lanes) per node,
// lane = feature index. All scaling (d^-1/2 both sides, re_norm recurrence)
// fused into the gather epilogues.

#define DF 64

__global__ void count_kernel(const int* __restrict__ dst, int* __restrict__ deg, int E) {
    int e = blockIdx.x * blockDim.x + threadIdx.x;
    if (e < E) atomicAdd(&deg[dst[e]], 1);
}

__global__ void dinv_kernel(const int* __restrict__ deg, float* __restrict__ dinv, int n) {
    int i = blockIdx.x * blockDim.x + threadIdx.x;
    if (i < n) {
        int d = deg[i];
        if (d < 1) d = 1;
        dinv[i] = rsqrtf((float)d);
    }
}

// Single-block scan: each thread serial-scans 8 items, block Hillis-Steele over
// the 1024 thread sums, carry across 8K-element chunks. n=60000 -> 8 chunks.
__global__ __launch_bounds__(1024) void scan_kernel(const int* __restrict__ deg,
                                                    int* __restrict__ rowptr,
                                                    int* __restrict__ cursor, int n) {
    __shared__ int sh[1024];
    __shared__ int carry_sh;
    const int tid = threadIdx.x;
    if (tid == 0) carry_sh = 0;
    __syncthreads();
    const int ITEMS = 8;
    const int CHUNK = 1024 * ITEMS;
    for (int base = 0; base < n; base += CHUNK) {
        int v[ITEMS];
        int tsum = 0;
        int start = base + tid * ITEMS;
        #pragma unroll
        for (int j = 0; j < ITEMS; j++) {
            int idx = start + j;
            int d = (idx < n) ? deg[idx] : 0;
            v[j] = tsum;           // exclusive within-thread prefix
            tsum += d;
        }
        sh[tid] = tsum;
        __syncthreads();
        for (int off = 1; off < 1024; off <<= 1) {
            int x = sh[tid];
            int y = (tid >= off) ? sh[tid - off] : 0;
            __syncthreads();
            sh[tid] = x + y;
            __syncthreads();
        }
        int incl = sh[tid];
        int excl = incl - tsum + carry_sh;
        #pragma unroll
        for (int j = 0; j < ITEMS; j++) {
            int idx = start + j;
            if (idx < n) {
                int val = excl + v[j];
                rowptr[idx] = val;
                cursor[idx] = val;
            }
        }
        __syncthreads();
        if (tid == 1023) carry_sh += incl;  // incl == chunk total for tid 1023
        __syncthreads();
    }
    if (tid == 0) rowptr[n] = carry_sh;
}

__global__ void fill_kernel(const int* __restrict__ src, const int* __restrict__ dst,
                            int* __restrict__ cursor, int* __restrict__ col, int E) {
    int e = blockIdx.x * blockDim.x + threadIdx.x;
    if (e < E) {
        int d = dst[e];
        int pos = atomicAdd(&cursor[d], 1);
        col[pos] = src[e];
    }
}

// X1 = (rn-1)*X0 - rn * dinv[n] * sum_{s in N(n)} feat[s]*dinv[s]
// out[:,0:64] = relu(X0); out[:,64:128] = relu(X1); X1 stored raw in ws.
__global__ __launch_bounds__(256) void prop1_kernel(
    const float* __restrict__ feat, const int* __restrict__ rowptr,
    const int* __restrict__ col, const float* __restrict__ dinv,
    const float* __restrict__ lambda_max,
    float* __restrict__ x1, float* __restrict__ out, int n) {
    int node = (int)((blockIdx.x * blockDim.x + threadIdx.x) >> 6);
    int lane = threadIdx.x & 63;
    if (node >= n) return;
    int beg = rowptr[node], end = rowptr[node + 1];
    float acc = 0.f;
    for (int i = beg; i < end; i++) {
        int s = col[i];
        acc += feat[(size_t)s * DF + lane] * dinv[s];
    }
    float rn = 2.0f / lambda_max[0];
    float h = dinv[node] * acc;
    float x0v = feat[(size_t)node * DF + lane];
    float x1v = (rn - 1.0f) * x0v - rn * h;
    x1[(size_t)node * DF + lane] = x1v;
    size_t o = (size_t)node * (3 * DF);
    out[o + lane] = fmaxf(x0v, 0.f);
    out[o + DF + lane] = fmaxf(x1v, 0.f);
}

// X2 = 2*(rn-1)*X1 - 2*rn * dinv[n] * sum feat-gather(X1) - X0
__global__ __launch_bounds__(256) void prop2_kernel(
    const float* __restrict__ feat, const float* __restrict__ x1,
    const int* __restrict__ rowptr, const int* __restrict__ col,
    const float* __restrict__ dinv, const float* __restrict__ lambda_max,
    float* __restrict__ out, int n) {
    int node = (int)((blockIdx.x * blockDim.x + threadIdx.x) >> 6);
    int lane = threadIdx.x & 63;
    if (node >= n) return;
    int beg = rowptr[node], end = rowptr[node + 1];
    float acc = 0.f;
    for (int i = beg; i < end; i++) {
        int s = col[i];
        acc += x1[(size_t)s * DF + lane] * dinv[s];
    }
    float rn = 2.0f / lambda_max[0];
    float h = dinv[node] * acc;
    float x0v = feat[(size_t)node * DF + lane];
    float x1v = x1[(size_t)node * DF + lane];
    float x2v = 2.0f * (rn - 1.0f) * x1v - 2.0f * rn * h - x0v;
    size_t o = (size_t)node * (3 * DF);
    out[o + 2 * DF + lane] = fmaxf(x2v, 0.f);
}

extern "C" void kernel_launch(void* const* d_in, const int* in_sizes, int n_in,
                              void* d_out, int out_size, void* d_ws, size_t ws_size,
                              hipStream_t stream) {
    const float* feat = (const float*)d_in[0];
    const int* src = (const int*)d_in[1];
    const int* dst = (const int*)d_in[2];
    const float* lambda_max = (const float*)d_in[3];
    const int n = in_sizes[0] / DF;   // 60000
    const int E = in_sizes[1];        // 1200000
    float* out = (float*)d_out;

    char* ws = (char*)d_ws;
    int* deg = (int*)ws;        ws += (size_t)n * sizeof(int);
    int* rowptr = (int*)ws;     ws += (size_t)(n + 1) * sizeof(int);
    int* cursor = (int*)ws;     ws += (size_t)n * sizeof(int);
    float* dinv = (float*)ws;   ws += (size_t)n * sizeof(float);
    int* col = (int*)ws;        ws += (size_t)E * sizeof(int);
    float* x1 = (float*)ws;     // n*64 floats

    hipMemsetAsync(deg, 0, (size_t)n * sizeof(int), stream);
    count_kernel<<<(E + 255) / 256, 256, 0, stream>>>(dst, deg, E);
    scan_kernel<<<1, 1024, 0, stream>>>(deg, rowptr, cursor, n);
    dinv_kernel<<<(n + 255) / 256, 256, 0, stream>>>(deg, dinv, n);
    fill_kernel<<<(E + 255) / 256, 256, 0, stream>>>(src, dst, cursor, col, E);
    prop1_kernel<<<(n + 3) / 4, 256, 0, stream>>>(feat, rowptr, col, dinv, lambda_max, x1, out, n);
    prop2_kernel<<<(n + 3) / 4, 256, 0, stream>>>(feat, x1, rowptr, col, dinv, lambda_max, out, n);
}

// Round 2
// 310.887 us; speedup vs baseline: 1.6687x; 1.6687x over previous
//
#include <hip/hip_runtime.h>

// ChebConv K=3, D=64. CSR build (count -> parallel 3-kernel scan -> fill),
// then two atomic-free gather propagations.
// Gather layout: one wave per node; lane = (grp 0..3, sub 0..15);
// each lane loads float4 (4 features), 16 lanes cover a 64-float row,
// 4 edge rows in flight per wave iteration, unrolled x2 -> 8 edges in flight.

#define DF 64

__global__ void count_kernel(const int* __restrict__ dst, int* __restrict__ deg, int E) {
    int e = blockIdx.x * blockDim.x + threadIdx.x;
    if (e < E) atomicAdd(&deg[dst[e]], 1);
}

// scan1: block-local exclusive scan of deg into cursor; block sums -> bsum
__global__ __launch_bounds__(256) void scan1_kernel(const int* __restrict__ deg,
                                                    int* __restrict__ cursor,
                                                    int* __restrict__ bsum, int n) {
    __shared__ int sh[256];
    int tid = threadIdx.x;
    int i = blockIdx.x * 256 + tid;
    int v = (i < n) ? deg[i] : 0;
    sh[tid] = v;
    __syncthreads();
    for (int off = 1; off < 256; off <<= 1) {
        int x = sh[tid];
        int y = (tid >= off) ? sh[tid - off] : 0;
        __syncthreads();
        sh[tid] = x + y;
        __syncthreads();
    }
    int incl = sh[tid];
    if (i < n) cursor[i] = incl - v;      // exclusive within block
    if (tid == 255) bsum[blockIdx.x] = incl;
}

// scan2: exclusive scan of the (<=1024) block sums; total -> rowptr[n]
__global__ __launch_bounds__(1024) void scan2_kernel(const int* __restrict__ bsum,
                                                     int* __restrict__ bpre, int nb,
                                                     int* __restrict__ rowptr_end) {
    __shared__ int sh[1024];
    int tid = threadIdx.x;
    int v = (tid < nb) ? bsum[tid] : 0;
    sh[tid] = v;
    __syncthreads();
    for (int off = 1; off < 1024; off <<= 1) {
        int x = sh[tid];
        int y = (tid >= off) ? sh[tid - off] : 0;
        __syncthreads();
        sh[tid] = x + y;
        __syncthreads();
    }
    int incl = sh[tid];
    if (tid < nb) bpre[tid] = incl - v;
    if (tid == 1023) *rowptr_end = incl;  // total edge count
}

// scan3: add block offsets -> rowptr & cursor; fuse dinv computation
__global__ __launch_bounds__(256) void scan3_kernel(const int* __restrict__ deg,
                                                    const int* __restrict__ bpre,
                                                    int* __restrict__ rowptr,
                                                    int* __restrict__ cursor,
                                                    float* __restrict__ dinv, int n) {
    int i = blockIdx.x * 256 + threadIdx.x;
    if (i < n) {
        int val = cursor[i] + bpre[i >> 8];
        rowptr[i] = val;
        cursor[i] = val;
        int d = deg[i];
        if (d < 1) d = 1;
        dinv[i] = rsqrtf((float)d);
    }
}

__global__ void fill_kernel(const int* __restrict__ src, const int* __restrict__ dst,
                            int* __restrict__ cursor, int* __restrict__ col, int E) {
    int e = blockIdx.x * blockDim.x + threadIdx.x;
    if (e < E) {
        int d = dst[e];
        int pos = atomicAdd(&cursor[d], 1);
        col[pos] = src[e];
    }
}

// X1 = (rn-1)*X0 - rn * dinv[n] * sum_{s in N(n)} feat[s]*dinv[s]
__global__ __launch_bounds__(256) void prop1_kernel(
    const float* __restrict__ feat, const int* __restrict__ rowptr,
    const int* __restrict__ col, const float* __restrict__ dinv,
    const float* __restrict__ lambda_max,
    float* __restrict__ x1, float* __restrict__ out, int n) {
    int node = (int)((blockIdx.x * blockDim.x + threadIdx.x) >> 6);
    if (node >= n) return;
    int lane = threadIdx.x & 63;
    int grp = lane >> 4;   // which of 4 edges in flight
    int sub = lane & 15;   // float4 segment within the row
    int beg = rowptr[node], end = rowptr[node + 1];
    float ax = 0.f, ay = 0.f, az = 0.f, aw = 0.f;
    int i = beg + grp;
    for (; i + 4 < end; i += 8) {
        int s0 = col[i], s1 = col[i + 4];
        float4 v0 = *(const float4*)(feat + (size_t)s0 * DF + sub * 4);
        float4 v1 = *(const float4*)(feat + (size_t)s1 * DF + sub * 4);
        float w0 = dinv[s0], w1 = dinv[s1];
        ax += v0.x * w0 + v1.x * w1;
        ay += v0.y * w0 + v1.y * w1;
        az += v0.z * w0 + v1.z * w1;
        aw += v0.w * w0 + v1.w * w1;
    }
    if (i < end) {
        int s0 = col[i];
        float4 v0 = *(const float4*)(feat + (size_t)s0 * DF + sub * 4);
        float w0 = dinv[s0];
        ax += v0.x * w0; ay += v0.y * w0; az += v0.z * w0; aw += v0.w * w0;
    }
    ax += __shfl_xor(ax, 16); ax += __shfl_xor(ax, 32);
    ay += __shfl_xor(ay, 16); ay += __shfl_xor(ay, 32);
    az += __shfl_xor(az, 16); az += __shfl_xor(az, 32);
    aw += __shfl_xor(aw, 16); aw += __shfl_xor(aw, 32);
    if (grp == 0) {
        float rn = 2.0f / lambda_max[0];
        float dn = dinv[node];
        float c1 = rn - 1.0f;
        float4 x0 = *(const float4*)(feat + (size_t)node * DF + sub * 4);
        float4 x1v;
        x1v.x = c1 * x0.x - rn * dn * ax;
        x1v.y = c1 * x0.y - rn * dn * ay;
        x1v.z = c1 * x0.z - rn * dn * az;
        x1v.w = c1 * x0.w - rn * dn * aw;
        *(float4*)(x1 + (size_t)node * DF + sub * 4) = x1v;
        size_t o = (size_t)node * (3 * DF);
        float4 r0 = make_float4(fmaxf(x0.x, 0.f), fmaxf(x0.y, 0.f), fmaxf(x0.z, 0.f), fmaxf(x0.w, 0.f));
        float4 r1 = make_float4(fmaxf(x1v.x, 0.f), fmaxf(x1v.y, 0.f), fmaxf(x1v.z, 0.f), fmaxf(x1v.w, 0.f));
        *(float4*)(out + o + sub * 4) = r0;
        *(float4*)(out + o + DF + sub * 4) = r1;
    }
}

// X2 = 2*(rn-1)*X1 - 2*rn * dinv[n] * gather(X1) - X0
__global__ __launch_bounds__(256) void prop2_kernel(
    const float* __restrict__ feat, const float* __restrict__ x1,
    const int* __restrict__ rowptr, const int* __restrict__ col,
    const float* __restrict__ dinv, const float* __restrict__ lambda_max,
    float* __restrict__ out, int n) {
    int node = (int)((blockIdx.x * blockDim.x + threadIdx.x) >> 6);
    if (node >= n) return;
    int lane = threadIdx.x & 63;
    int grp = lane >> 4;
    int sub = lane & 15;
    int beg = rowptr[node], end = rowptr[node + 1];
    float ax = 0.f, ay = 0.f, az = 0.f, aw = 0.f;
    int i = beg + grp;
    for (; i + 4 < end; i += 8) {
        int s0 = col[i], s1 = col[i + 4];
        float4 v0 = *(const float4*)(x1 + (size_t)s0 * DF + sub * 4);
        float4 v1 = *(const float4*)(x1 + (size_t)s1 * DF + sub * 4);
        float w0 = dinv[s0], w1 = dinv[s1];
        ax += v0.x * w0 + v1.x * w1;
        ay += v0.y * w0 + v1.y * w1;
        az += v0.z * w0 + v1.z * w1;
        aw += v0.w * w0 + v1.w * w1;
    }
    if (i < end) {
        int s0 = col[i];
        float4 v0 = *(const float4*)(x1 + (size_t)s0 * DF + sub * 4);
        float w0 = dinv[s0];
        ax += v0.x * w0; ay += v0.y * w0; az += v0.z * w0; aw += v0.w * w0;
    }
    ax += __shfl_xor(ax, 16); ax += __shfl_xor(ax, 32);
    ay += __shfl_xor(ay, 16); ay += __shfl_xor(ay, 32);
    az += __shfl_xor(az, 16); az += __shfl_xor(az, 32);
    aw += __shfl_xor(aw, 16); aw += __shfl_xor(aw, 32);
    if (grp == 0) {
        float rn = 2.0f / lambda_max[0];
        float dn = dinv[node];
        float c2 = 2.0f * (rn - 1.0f);
        float4 x0 = *(const float4*)(feat + (size_t)node * DF + sub * 4);
        float4 x1v = *(const float4*)(x1 + (size_t)node * DF + sub * 4);
        float4 x2v;
        x2v.x = c2 * x1v.x - 2.0f * rn * dn * ax - x0.x;
        x2v.y = c2 * x1v.y - 2.0f * rn * dn * ay - x0.y;
        x2v.z = c2 * x1v.z - 2.0f * rn * dn * az - x0.z;
        x2v.w = c2 * x1v.w - 2.0f * rn * dn * aw - x0.w;
        size_t o = (size_t)node * (3 * DF);
        float4 r2 = make_float4(fmaxf(x2v.x, 0.f), fmaxf(x2v.y, 0.f), fmaxf(x2v.z, 0.f), fmaxf(x2v.w, 0.f));
        *(float4*)(out + o + 2 * DF + sub * 4) = r2;
    }
}

extern "C" void kernel_launch(void* const* d_in, const int* in_sizes, int n_in,
                              void* d_out, int out_size, void* d_ws, size_t ws_size,
                              hipStream_t stream) {
    const float* feat = (const float*)d_in[0];
    const int* src = (const int*)d_in[1];
    const int* dst = (const int*)d_in[2];
    const float* lambda_max = (const float*)d_in[3];
    const int n = in_sizes[0] / DF;   // 60000
    const int E = in_sizes[1];        // 1200000
    float* out = (float*)d_out;

    auto align256 = [](size_t x) { return (x + 255) & ~(size_t)255; };
    char* ws = (char*)d_ws;
    int* deg = (int*)ws;        ws += align256((size_t)n * sizeof(int));
    int* rowptr = (int*)ws;     ws += align256((size_t)(n + 1) * sizeof(int));
    int* cursor = (int*)ws;     ws += align256((size_t)n * sizeof(int));
    float* dinv = (float*)ws;   ws += align256((size_t)n * sizeof(float));
    int* bsum = (int*)ws;       ws += align256((size_t)1024 * sizeof(int));
    int* bpre = (int*)ws;       ws += align256((size_t)1024 * sizeof(int));
    int* col = (int*)ws;        ws += align256((size_t)E * sizeof(int));
    float* x1 = (float*)ws;     // n*64 floats, 256B-aligned

    const int nb = (n + 255) / 256;   // 235 scan blocks

    hipMemsetAsync(deg, 0, (size_t)n * sizeof(int), stream);
    count_kernel<<<(E + 255) / 256, 256, 0, stream>>>(dst, deg, E);
    scan1_kernel<<<nb, 256, 0, stream>>>(deg, cursor, bsum, n);
    scan2_kernel<<<1, 1024, 0, stream>>>(bsum, bpre, nb, rowptr + n);
    scan3_kernel<<<nb, 256, 0, stream>>>(deg, bpre, rowptr, cursor, dinv, n);
    fill_kernel<<<(E + 255) / 256, 256, 0, stream>>>(src, dst, cursor, col, E);
    prop1_kernel<<<(n + 3) / 4, 256, 0, stream>>>(feat, rowptr, col, dinv, lambda_max, x1, out, n);
    prop2_kernel<<<(n + 3) / 4, 256, 0, stream>>>(feat, x1, rowptr, col, dinv, lambda_max, out, n);
}